// Round 4
// baseline (39984.393 us; speedup 1.0000x reference)
//
#include <hip/hip_runtime.h>

#define EPSF 1e-5f

typedef unsigned short u16;
typedef unsigned int u32;

__device__ __forceinline__ u16 f2bf(float f) {
  u32 u = __float_as_uint(f);
  u += 0x7fffu + ((u >> 16) & 1u);   // RNE
  return (u16)(u >> 16);
}
__device__ __forceinline__ u32 packbf(float lo, float hi) {
  return (u32)f2bf(lo) | ((u32)f2bf(hi) << 16);
}

#if __has_builtin(__builtin_amdgcn_fdot2_f32_bf16)
typedef __attribute__((ext_vector_type(2))) __bf16 bf16x2;
__device__ __forceinline__ float dot2bf(u32 w, u32 h, float acc) {
  union { u32 u; bf16x2 v; } a, b; a.u = w; b.u = h;
  return __builtin_amdgcn_fdot2_f32_bf16(a.v, b.v, acc, false);
}
#else
__device__ __forceinline__ float dot2bf(u32 w, u32 h, float acc) {
  float r = fmaf(__uint_as_float(w << 16), __uint_as_float(h << 16), acc);
  return fmaf(__uint_as_float(w & 0xffff0000u), __uint_as_float(h & 0xffff0000u), r);
}
#endif

// W1p: u16 idx (kk*1024 + j)*8 + r = bf16(W1[j][kk*8+r]), kk 0..63
// W2p: u16 idx (kk*512  + n)*8 + r = bf16(W2[n][kk*8+r]), kk 0..63
__global__ void prep_weights(const float* __restrict__ W1, const float* __restrict__ W2,
                             u16* __restrict__ W1p, u16* __restrict__ W2p) {
  int i = blockIdx.x * blockDim.x + threadIdx.x;
  if (i < 1024 * 64) {
    int j = i >> 6, kk = i & 63;
    const float* src = W1 + (size_t)j * 512 + kk * 8;
    u16* dst = W1p + ((size_t)(kk * 1024 + j)) * 8;
    #pragma unroll
    for (int r = 0; r < 8; ++r) dst[r] = f2bf(src[r]);
  }
  if (i < 512 * 64) {
    int n = i >> 6, kk = i & 63;
    const float* src = W2 + (size_t)n * 512 + kk * 8;
    u16* dst = W2p + ((size_t)(kk * 512 + n)) * 8;
    #pragma unroll
    for (int r = 0; r < 8; ++r) dst[r] = f2bf(src[r]);
  }
}

__global__ __launch_bounds__(1024)
void rnn_kernel(const float* __restrict__ xs, const float* __restrict__ h0,
                const float* __restrict__ gamma, const float* __restrict__ beta,
                const u16* __restrict__ W1p,
                const float* __restrict__ lnh_w, const float* __restrict__ lnh_b,
                const u16* __restrict__ W2p,
                const float* __restrict__ lnx_w, const float* __restrict__ lnx_b,
                float* __restrict__ out) {
  const int b = blockIdx.x;
  const int tid = threadIdx.x;
  const int N = 512;

  __shared__ float hg_s[512];
  __shared__ float p2[1024];
  __shared__ u32 hb2[256];
  __shared__ u32 xb2[256];
  __shared__ float red_s[16], red_q[16];
  __shared__ __align__(16) float out_t[32][512];   // 64 KB, conflict-free

  const int w = tid >> 6;

  // persistent per-thread params
  const float w1w = lnh_w[tid], w1b = lnh_b[tid];
  float g0 = 0, g1 = 0, g2 = 0, b0 = 0, b1 = 0, b2 = 0, w2w = 0, w2b = 0;
  float hv = 0.f, xv = 0.f, il = 0.f;
  if (tid < N) {
    g0 = gamma[0 * N + tid]; g1 = gamma[1 * N + tid]; g2 = gamma[2 * N + tid];
    b0 = beta[0 * N + tid];  b1 = beta[1 * N + tid];  b2 = beta[2 * N + tid];
    w2w = lnx_w[tid]; w2b = lnx_b[tid];
    hv = h0[(size_t)b * N + tid];
    float hnb = __shfl_down(hv, 1);
    if (!(tid & 1)) hb2[tid >> 1] = packbf(hv, hnb);
  }
  const float* xs_b = xs + (size_t)b * 3 * N * 1024;
  const uint4* w1 = ((const uint4*)W1p) + tid;                 // elem kk at w1[kk*1024]
  const int n2 = tid & 511, half = tid >> 9;
  const uint4* w2 = ((const uint4*)W2p) + n2 + (size_t)half * 32 * 512;  // kk local 0..31 at w2[kk*512]
  __syncthreads();

  for (int t0 = 0; t0 < 1024; t0 += 4) {
    float4 xr0, xr1, xr2;
    if (tid < N) {
      xr0 = *(const float4*)(xs_b + (size_t)(0 * N + tid) * 1024 + t0);
      xr1 = *(const float4*)(xs_b + (size_t)(1 * N + tid) * 1024 + t0);
      xr2 = *(const float4*)(xs_b + (size_t)(2 * N + tid) * 1024 + t0);
    }
    #pragma unroll
    for (int q = 0; q < 4; ++q) {
      const int t = t0 + q;
      const int tt = t & 31;

      // ---- mm1 with explicit 8-deep prefetch ----
      float acc;
      {
        const uint4* hp = (const uint4*)hb2;       // wave-uniform broadcast reads
        uint4 wv[8];
        #pragma unroll
        for (int u = 0; u < 8; ++u) wv[u] = w1[u * 1024];

        // in_layer overlapped with first weight-chunk latency
        if (tid < N) {
          float s0 = 1.f / (1.f + __expf(-(g0 * hv + b0)));
          float s1 = 1.f / (1.f + __expf(-(g1 * hv + b1)));
          float s2 = 1.f / (1.f + __expf(-(g2 * hv + b2)));
          float x0 = (q == 0) ? xr0.x : (q == 1) ? xr0.y : (q == 2) ? xr0.z : xr0.w;
          float x1 = (q == 0) ? xr1.x : (q == 1) ? xr1.y : (q == 2) ? xr1.z : xr1.w;
          float x2 = (q == 0) ? xr2.x : (q == 1) ? xr2.y : (q == 2) ? xr2.z : xr2.w;
          il = fmaxf(s0 * x0 + s1 * x1 + s2 * x2, 0.f);
        }

        float a0 = 0.f, a1 = 0.f, a2 = 0.f, a3 = 0.f;
        #pragma unroll
        for (int c = 0; c < 8; ++c) {
          uint4 nx[8];
          #pragma unroll
          for (int u = 0; u < 8; ++u)
            if (c < 7) nx[u] = w1[((c + 1) * 8 + u) * 1024];
          #pragma unroll
          for (int u = 0; u < 8; ++u) {
            uint4 hv4 = hp[c * 8 + u];
            a0 = dot2bf(wv[u].x, hv4.x, a0); a1 = dot2bf(wv[u].y, hv4.y, a1);
            a2 = dot2bf(wv[u].z, hv4.z, a2); a3 = dot2bf(wv[u].w, hv4.w, a3);
          }
          #pragma unroll
          for (int u = 0; u < 8; ++u) wv[u] = nx[u];
        }
        acc = (a0 + a1) + (a2 + a3);
      }

      // ---- LN1: wave reduce + one barrier + redundant fold ----
      {
        float s = acc, qq = acc * acc;
        #pragma unroll
        for (int off = 32; off > 0; off >>= 1) {
          s += __shfl_down(s, off); qq += __shfl_down(qq, off);
        }
        if ((tid & 63) == 0) { red_s[w] = s; red_q[w] = qq; }
      }
      __syncthreads();                                   // B1
      float mu, rinv;
      {
        float s = red_s[tid & 15], qq = red_q[tid & 15];
        #pragma unroll
        for (int off = 8; off > 0; off >>= 1) {
          s += __shfl_xor(s, off); qq += __shfl_xor(qq, off);
        }
        mu = s * (1.f / 1024.f);
        float var = qq * (1.f / 1024.f) - mu * mu;
        rinv = rsqrtf(var + EPSF);
      }

      // ---- LN1 apply: x and h_g ----
      {
        float hh = (acc - mu) * rinv * w1w + w1b;
        if (tid < N) {
          xv = fmaxf(il + hh, 0.f);
          float xnb = __shfl_down(xv, 1);
          if (!(tid & 1)) xb2[tid >> 1] = packbf(xv, xnb);
        } else {
          hg_s[tid - N] = hh;
        }
      }
      __syncthreads();                                   // B2

      // ---- mm2: k-split halves, 8-deep prefetch ----
      {
        const uint4* xp = ((const uint4*)xb2) + half * 32;
        uint4 wv[8];
        #pragma unroll
        for (int u = 0; u < 8; ++u) wv[u] = w2[u * 512];
        float c0 = 0.f, c1 = 0.f, c2 = 0.f, c3 = 0.f;
        #pragma unroll
        for (int c = 0; c < 4; ++c) {
          uint4 nx[8];
          #pragma unroll
          for (int u = 0; u < 8; ++u)
            if (c < 3) nx[u] = w2[((c + 1) * 8 + u) * 512];
          #pragma unroll
          for (int u = 0; u < 8; ++u) {
            uint4 xv4 = xp[c * 8 + u];
            c0 = dot2bf(wv[u].x, xv4.x, c0); c1 = dot2bf(wv[u].y, xv4.y, c1);
            c2 = dot2bf(wv[u].z, xv4.z, c2); c3 = dot2bf(wv[u].w, xv4.w, c3);
          }
          #pragma unroll
          for (int u = 0; u < 8; ++u) wv[u] = nx[u];
        }
        p2[tid] = (c0 + c1) + (c2 + c3);
      }
      __syncthreads();                                   // B3

      // ---- LN2: combine + wave reduce + one barrier + fold ----
      float accf = 0.f;
      {
        float s = 0.f, qq = 0.f;
        if (tid < N) {
          accf = p2[tid] + p2[tid + 512];
          s = accf; qq = accf * accf;
        }
        #pragma unroll
        for (int off = 32; off > 0; off >>= 1) {
          s += __shfl_down(s, off); qq += __shfl_down(qq, off);
        }
        if ((tid & 63) == 0) { red_s[w] = s; red_q[w] = qq; }
      }
      __syncthreads();                                   // B4
      {
        float s = red_s[tid & 15], qq = red_q[tid & 15];
        #pragma unroll
        for (int off = 8; off > 0; off >>= 1) {
          s += __shfl_xor(s, off); qq += __shfl_xor(qq, off);
        }
        float mu2 = s * (1.f / 512.f);
        float var2 = qq * (1.f / 512.f) - mu2 * mu2;
        float rinv2 = rsqrtf(var2 + EPSF);

        // ---- gate + state update ----
        if (tid < N) {
          float y = (accf - mu2) * rinv2 * w2w + w2b;
          float gg = 1.f / (1.f + __expf(-(y + hg_s[tid])));
          float hn = hv + gg * (xv - hv);
          out_t[tt][tid] = hn;
          hv = hn;
          float hnb = __shfl_down(hn, 1);
          if (!(tid & 1)) hb2[tid >> 1] = packbf(hn, hnb);
        }
      }
      __syncthreads();                                   // B5

      // ---- flush out tile every 32 steps ----
      if (tt == 31) {
        const int n = tid >> 1;
        const int seg = tid & 1;
        float* op = out + ((size_t)b * N + n) * 1024 + (t - 31) + seg * 16;
        #pragma unroll
        for (int i = 0; i < 4; ++i) {
          float4 v;
          v.x = out_t[seg * 16 + i * 4 + 0][n];
          v.y = out_t[seg * 16 + i * 4 + 1][n];
          v.z = out_t[seg * 16 + i * 4 + 2][n];
          v.w = out_t[seg * 16 + i * 4 + 3][n];
          *(float4*)(op + i * 4) = v;
        }
      }
    }
  }
}

extern "C" void kernel_launch(void* const* d_in, const int* in_sizes, int n_in,
                              void* d_out, int out_size, void* d_ws, size_t ws_size,
                              hipStream_t stream) {
  const float* xs    = (const float*)d_in[0];
  const float* h0    = (const float*)d_in[1];
  const float* gamma = (const float*)d_in[2];
  const float* beta  = (const float*)d_in[3];
  const float* W1    = (const float*)d_in[4];
  const float* lnh_w = (const float*)d_in[5];
  const float* lnh_b = (const float*)d_in[6];
  const float* W2    = (const float*)d_in[7];
  const float* lnx_w = (const float*)d_in[8];
  const float* lnx_b = (const float*)d_in[9];
  float* out = (float*)d_out;

  u16* W1p = (u16*)d_ws;                    // 1 MB
  u16* W2p = W1p + (size_t)1024 * 512;      // 0.5 MB

  prep_weights<<<(65536 + 255) / 256, 256, 0, stream>>>(W1, W2, W1p, W2p);
  rnn_kernel<<<64, 1024, 0, stream>>>(xs, h0, gamma, beta, W1p,
                                      lnh_w, lnh_b, W2p, lnx_w, lnx_b, out);
}